// Round 12
// baseline (399.957 us; speedup 1.0000x reference)
//
#include <hip/hip_runtime.h>
#include <hip/hip_bf16.h>
#include <cstdint>

// ---------------------------------------------------------------------------
// GraphRLAgent: 2-layer GAT (heads=2 then 1) + global mean pool + 2 heads.
// Round 12:
//  - separable exp: w = exp(leaky(es+ed)) == (A.x*B.x>1)? A.x*B.x : A.y*B.y
//    with eA=(e^es, e^.2es), eB=(e^ed, e^.2ed) precomputed in the GEMM
//    epilogue via LDS reduction (atomics + es/ed zeroing deleted; edge loop
//    loses its transcendental).
//  - scatter ∥ gemm1 in ONE kernel, interleaved block roles (every 4th block
//    is GEMM) — gemm1 hides under the scatter's random-write latency.
//  - swizzle folded into the zero/init kernel. 10 dispatches.
// ---------------------------------------------------------------------------

typedef __attribute__((ext_vector_type(8))) short bf16x8;
typedef __attribute__((ext_vector_type(4))) float f32x4;

__device__ __forceinline__ unsigned short f2bf(float f) {
    union { float f; uint32_t u; } c; c.f = f;
    uint32_t u = c.u;
    return (unsigned short)((u + 0x7fffu + ((u >> 16) & 1u)) >> 16);
}

__device__ __forceinline__ float bf2f(unsigned short u) {
    union { uint32_t u; float f; } c; c.u = ((uint32_t)u) << 16;
    return c.f;
}

// ------------------------- B swizzle body ---------------------------------

template <int K, int FOUT>
__device__ __forceinline__ void swizzle_body(const float* __restrict__ W,
                                             unsigned short* __restrict__ Bsw, int tid) {
    constexpr int CPW = FOUT / 4, NCT = CPW / 16, KST = K / 32;
    if (tid >= K * FOUT / 8) return;
    int lane = tid & 63;
    int rest = tid >> 6;
    int t = rest % KST; rest /= KST;
    int c = rest % NCT; rest /= NCT;
    int cg_ = rest;
    int quad = lane >> 4, lo = lane & 15;
    int col = cg_ * CPW + c * 16 + lo;
    unsigned short v[8];
#pragma unroll
    for (int j = 0; j < 8; ++j)
        v[j] = f2bf(W[(t * 32 + quad * 8 + j) * FOUT + col]);
    ushort4* dst = (ushort4*)(Bsw + (size_t)tid * 8);
    ushort4 o0, o1;
    o0.x = v[0]; o0.y = v[1]; o0.z = v[2]; o0.w = v[3];
    o1.x = v[4]; o1.y = v[5]; o1.z = v[6]; o1.w = v[7];
    dst[0] = o0; dst[1] = o1;
}

// ------------------------- init: zero + swizzle ---------------------------

__global__ void init_kernel(const float* __restrict__ W1, const float* __restrict__ W2,
                            unsigned short* __restrict__ B1, unsigned short* __restrict__ B2,
                            int* __restrict__ zbase, int zn4) {
    int b = blockIdx.x;
    if (b < 16)       swizzle_body<128, 256>(W1, B1, b * 256 + threadIdx.x);
    else if (b < 32)  swizzle_body<256, 128>(W2, B2, (b - 16) * 256 + threadIdx.x);
    else {
        int i = (b - 32) * 256 + threadIdx.x;
        if (i < zn4) ((int4*)zbase)[i] = make_int4(0, 0, 0, 0);
    }
}

// ------------------------- CSR construction -------------------------------

__global__ void degree_kernel(const int* __restrict__ ei, int* __restrict__ deg,
                              int E, int N) {
    int i = blockIdx.x * blockDim.x + threadIdx.x;
    if (i >= E + N) return;
    int dst = (i < E) ? ei[E + i] : (i - E);
    atomicAdd(&deg[dst], 1);
}

__global__ __launch_bounds__(256) void scan_tiles(int* __restrict__ deg,
                                                  int* __restrict__ tsum, int N) {
    __shared__ int buf[256];
    const int t = threadIdx.x;
    const int base = blockIdx.x * 1024 + t * 4;
    int v[4]; int s = 0;
#pragma unroll
    for (int k = 0; k < 4; ++k) { v[k] = (base + k < N) ? deg[base + k] : 0; s += v[k]; }
    buf[t] = s;
    __syncthreads();
#pragma unroll
    for (int off = 1; off < 256; off <<= 1) {
        int x = (t >= off) ? buf[t - off] : 0;
        __syncthreads();
        buf[t] += x;
        __syncthreads();
    }
    int run = buf[t] - s;
#pragma unroll
    for (int k = 0; k < 4; ++k) {
        if (base + k < N) deg[base + k] = run;
        run += v[k];
    }
    if (t == 255) tsum[blockIdx.x] = buf[255];
}

__global__ __launch_bounds__(256) void scan_add(const int* __restrict__ partial,
                                                const int* __restrict__ tsum,
                                                int* __restrict__ rowptr,
                                                int* __restrict__ cursor, int N, int T) {
    __shared__ int s_toff;
    const int tile = blockIdx.x;
    if (threadIdx.x < 64) {
        int t = threadIdx.x;
        int v = (t < T) ? tsum[t] : 0;
#pragma unroll
        for (int off = 1; off < 64; off <<= 1) {
            int x = __shfl_up(v, off, 64);
            if (t >= off) v += x;
        }
        int toff = (tile == 0) ? 0 : __shfl(v, tile - 1, 64);
        if (t == 0) s_toff = toff;
        if (tile == 0 && t == 63) rowptr[N] = v;
    }
    __syncthreads();
    const int toff = s_toff;
    int i = tile * 1024 + threadIdx.x * 4;
#pragma unroll
    for (int k = 0; k < 4; ++k) {
        if (i + k < N) {
            int r = partial[i + k] + toff;
            rowptr[i + k] = r;
            cursor[i + k] = r;
        }
    }
}

__device__ __forceinline__ void scatter_body(const int* __restrict__ ei,
                                             int* __restrict__ cursor,
                                             int* __restrict__ csr_src, int E, int N, int i) {
    if (i >= E + N) return;
    int src, dst;
    if (i < E) { src = ei[i]; dst = ei[E + i]; }
    else       { src = dst = i - E; }
    int pos = atomicAdd(&cursor[dst], 1);
    csr_src[pos] = src;
}

// ------------------------- bf16 MFMA GEMM body + exp-coef epilogue --------
// C[N,FOUT](bf16) = A x B (fp32 acc). Epilogue: per-row dots with a_src/a_dst
// reduced via LDS (rows are block-exclusive), then eA=(e^ps, e^.2ps),
// eB=(e^pd, e^.2pd) stored as float2 — no atomics, no zero-init needed.

template <int K, int FOUT, int H, bool A32>
__device__ __forceinline__ void gemm_body(const void* __restrict__ Av,
                                          const unsigned short* __restrict__ Bsw,
                                          const float* __restrict__ a_src,
                                          const float* __restrict__ a_dst,
                                          float2* __restrict__ eA, float2* __restrict__ eB,
                                          unsigned short* __restrict__ C, int N, int bid) {
    constexpr int CPW = FOUT / 4;
    constexpr int NCT = CPW / 16;
    constexpr int KST = K / 32;
    const int tid = threadIdx.x;
    const int wave = tid >> 6, lane = tid & 63;
    const int quad = lane >> 4, lo = lane & 15;
    const int n0 = bid * 64;
    const int c0 = wave * CPW;
    __shared__ float lds_ps[4][64];
    __shared__ float lds_pd[4][64];

    bf16x8 bf[NCT][KST];
    {
        const bf16x8* Bp = (const bf16x8*)Bsw;
#pragma unroll
        for (int c = 0; c < NCT; ++c)
#pragma unroll
            for (int t = 0; t < KST; ++t)
                bf[c][t] = Bp[((wave * NCT + c) * KST + t) * 64 + lane];
    }

    f32x4 acc[4][NCT];
#pragma unroll
    for (int r = 0; r < 4; ++r)
#pragma unroll
        for (int c = 0; c < NCT; ++c) acc[r][c] = (f32x4){0.f, 0.f, 0.f, 0.f};

#pragma unroll
    for (int r = 0; r < 4; ++r) {
        const int arow = n0 + r * 16 + lo;
        if (A32) {
            const size_t rclamp = (arow < N) ? (size_t)arow : 0;
            const float* Ar = (const float*)Av + rclamp * K + quad * 8;
            const bool valid = arow < N;
#pragma unroll
            for (int t = 0; t < KST; ++t) {
                bf16x8 af;
                if (valid) {
                    float4 v0 = *(const float4*)(Ar + t * 32);
                    float4 v1 = *(const float4*)(Ar + t * 32 + 4);
                    af[0] = (short)f2bf(v0.x); af[1] = (short)f2bf(v0.y);
                    af[2] = (short)f2bf(v0.z); af[3] = (short)f2bf(v0.w);
                    af[4] = (short)f2bf(v1.x); af[5] = (short)f2bf(v1.y);
                    af[6] = (short)f2bf(v1.z); af[7] = (short)f2bf(v1.w);
                } else {
                    af = (bf16x8){0, 0, 0, 0, 0, 0, 0, 0};
                }
#pragma unroll
                for (int c = 0; c < NCT; ++c)
                    acc[r][c] = __builtin_amdgcn_mfma_f32_16x16x32_bf16(af, bf[c][t], acc[r][c],
                                                                       0, 0, 0);
            }
        } else {
            const unsigned short* Ar = (const unsigned short*)Av + (size_t)arow * K + quad * 8;
#pragma unroll
            for (int t = 0; t < KST; ++t) {
                bf16x8 af = *(const bf16x8*)(Ar + t * 32);
#pragma unroll
                for (int c = 0; c < NCT; ++c)
                    acc[r][c] = __builtin_amdgcn_mfma_f32_16x16x32_bf16(af, bf[c][t], acc[r][c],
                                                                       0, 0, 0);
            }
        }
    }

    // C/D layout: col = lane&15, row = quad*4 + j
#pragma unroll
    for (int r = 0; r < 4; ++r) {
        int row = n0 + r * 16 + quad * 4;
#pragma unroll
        for (int c = 0; c < NCT; ++c) {
            int col = c0 + c * 16 + lo;
#pragma unroll
            for (int j = 0; j < 4; ++j)
                if (row + j < N) C[(size_t)(row + j) * FOUT + col] = f2bf(acc[r][c][j]);
        }
    }

    // attention-coef partial dots -> LDS
    float asv[NCT], adv[NCT];
#pragma unroll
    for (int c = 0; c < NCT; ++c) {
        int col = c0 + c * 16 + lo;
        asv[c] = a_src[col];
        adv[c] = a_dst[col];
    }
#pragma unroll
    for (int r = 0; r < 4; ++r) {
#pragma unroll
        for (int j = 0; j < 4; ++j) {
            float ps = 0.f, pd = 0.f;
#pragma unroll
            for (int c = 0; c < NCT; ++c) { ps += acc[r][c][j] * asv[c]; pd += acc[r][c][j] * adv[c]; }
#pragma unroll
            for (int off = 1; off <= 8; off <<= 1) {
                ps += __shfl_xor(ps, off, 64);
                pd += __shfl_xor(pd, off, 64);
            }
            if (lo == 0) {
                int row_l = r * 16 + quad * 4 + j;
                lds_ps[wave][row_l] = ps;
                lds_pd[wave][row_l] = pd;
            }
        }
    }
    __syncthreads();
    if (tid < 64 * H) {
        int row = tid & 63, h = tid >> 6;
        int n = n0 + row;
        if (n < N) {
            float ps, pd;
            if (H == 2) {
                ps = lds_ps[2 * h][row] + lds_ps[2 * h + 1][row];
                pd = lds_pd[2 * h][row] + lds_pd[2 * h + 1][row];
            } else {
                ps = lds_ps[0][row] + lds_ps[1][row] + lds_ps[2][row] + lds_ps[3][row];
                pd = lds_pd[0][row] + lds_pd[1][row] + lds_pd[2][row] + lds_pd[3][row];
            }
            eA[n * H + h] = make_float2(__expf(ps), __expf(0.2f * ps));
            eB[n * H + h] = make_float2(__expf(pd), __expf(0.2f * pd));
        }
    }
}

// standalone GEMM (layer 2)
template <int K, int FOUT, int H, bool A32>
__global__ __launch_bounds__(256) void gemm_mfma(const void* __restrict__ Av,
                                                 const unsigned short* __restrict__ Bsw,
                                                 const float* __restrict__ a_src,
                                                 const float* __restrict__ a_dst,
                                                 float2* __restrict__ eA, float2* __restrict__ eB,
                                                 unsigned short* __restrict__ C, int N) {
    gemm_body<K, FOUT, H, A32>(Av, Bsw, a_src, a_dst, eA, eB, C, N, blockIdx.x);
}

// fused scatter ∥ gemm1: every 4th block (bid&3==3, bid>>2<G) runs GEMM;
// the rest run scatter. Both finish before the kernel boundary.
__global__ __launch_bounds__(256) void scatter_gemm1(
    const int* __restrict__ ei, int* __restrict__ cursor, int* __restrict__ csrsrc,
    const float* __restrict__ x, const unsigned short* __restrict__ Bsw,
    const float* __restrict__ a_src, const float* __restrict__ a_dst,
    float2* __restrict__ eA, float2* __restrict__ eB, unsigned short* __restrict__ C,
    int E, int N, int G) {
    int bid = blockIdx.x;
    int g = bid >> 2;
    if ((bid & 3) == 3 && g < G) {
        gemm_body<128, 256, 2, true>(x, Bsw, a_src, a_dst, eA, eB, C, N, g);
    } else {
        int ng = (bid + 1) >> 2;
        if (ng > G) ng = G;
        int sid = bid - ng;
        scatter_body(ei, cursor, csrsrc, E, N, sid * 256 + threadIdx.x);
    }
}

// ------------------------- GAT aggregation, H=2 (single pass, no exp) -----

__global__ void gat_agg_h2(const unsigned short* __restrict__ Hpre,
                           const float2* __restrict__ eA, const float2* __restrict__ eB,
                           const int* __restrict__ rowptr, const int* __restrict__ csr_src,
                           const float* __restrict__ bias, unsigned short* __restrict__ out,
                           int N) {
    int wid = (blockIdx.x * blockDim.x + threadIdx.x) >> 6;
    int lane = threadIdx.x & 63;
    if (wid >= N) return;
    const int rs = rowptr[wid], re = rowptr[wid + 1];
    const int h = lane >> 5;
    const float2 Bv = eB[wid * 2 + h];

    float z = 0.f;
    float4 a0 = {0.f, 0.f, 0.f, 0.f}, a1 = {0.f, 0.f, 0.f, 0.f};
    float4 a2 = {0.f, 0.f, 0.f, 0.f}, a3 = {0.f, 0.f, 0.f, 0.f};
    int i = rs;
    for (; i + 4 <= re; i += 4) {
        int s0 = csr_src[i], s1 = csr_src[i + 1], s2 = csr_src[i + 2], s3 = csr_src[i + 3];
        float2 A0 = eA[s0 * 2 + h], A1 = eA[s1 * 2 + h];
        float2 A2 = eA[s2 * 2 + h], A3 = eA[s3 * 2 + h];
        float p0 = A0.x * Bv.x, p1 = A1.x * Bv.x, p2 = A2.x * Bv.x, p3 = A3.x * Bv.x;
        float w0 = (p0 > 1.f) ? p0 : A0.y * Bv.y;
        float w1 = (p1 > 1.f) ? p1 : A1.y * Bv.y;
        float w2 = (p2 > 1.f) ? p2 : A2.y * Bv.y;
        float w3 = (p3 > 1.f) ? p3 : A3.y * Bv.y;
        z += (w0 + w1) + (w2 + w3);
        ushort4 u0 = *(const ushort4*)(Hpre + (size_t)s0 * 256 + lane * 4);
        ushort4 u1 = *(const ushort4*)(Hpre + (size_t)s1 * 256 + lane * 4);
        ushort4 u2 = *(const ushort4*)(Hpre + (size_t)s2 * 256 + lane * 4);
        ushort4 u3 = *(const ushort4*)(Hpre + (size_t)s3 * 256 + lane * 4);
        a0.x += w0 * bf2f(u0.x); a0.y += w0 * bf2f(u0.y);
        a0.z += w0 * bf2f(u0.z); a0.w += w0 * bf2f(u0.w);
        a1.x += w1 * bf2f(u1.x); a1.y += w1 * bf2f(u1.y);
        a1.z += w1 * bf2f(u1.z); a1.w += w1 * bf2f(u1.w);
        a2.x += w2 * bf2f(u2.x); a2.y += w2 * bf2f(u2.y);
        a2.z += w2 * bf2f(u2.z); a2.w += w2 * bf2f(u2.w);
        a3.x += w3 * bf2f(u3.x); a3.y += w3 * bf2f(u3.y);
        a3.z += w3 * bf2f(u3.z); a3.w += w3 * bf2f(u3.w);
    }
    for (; i < re; ++i) {
        int s0 = csr_src[i];
        float2 A0 = eA[s0 * 2 + h];
        float p0 = A0.x * Bv.x;
        float w0 = (p0 > 1.f) ? p0 : A0.y * Bv.y;
        z += w0;
        ushort4 u0 = *(const ushort4*)(Hpre + (size_t)s0 * 256 + lane * 4);
        a0.x += w0 * bf2f(u0.x); a0.y += w0 * bf2f(u0.y);
        a0.z += w0 * bf2f(u0.z); a0.w += w0 * bf2f(u0.w);
    }
    const float rz = 1.f / (z + 1e-16f);
    float4 bv = ((const float4*)bias)[lane];
    float ox = (a0.x + a1.x + a2.x + a3.x) * rz + bv.x;
    float oy = (a0.y + a1.y + a2.y + a3.y) * rz + bv.y;
    float oz = (a0.z + a1.z + a2.z + a3.z) * rz + bv.z;
    float ow = (a0.w + a1.w + a2.w + a3.w) * rz + bv.w;
    ox = (ox > 0.f) ? ox : __expf(ox) - 1.f;
    oy = (oy > 0.f) ? oy : __expf(oy) - 1.f;
    oz = (oz > 0.f) ? oz : __expf(oz) - 1.f;
    ow = (ow > 0.f) ? ow : __expf(ow) - 1.f;
    ushort4 o;
    o.x = f2bf(ox); o.y = f2bf(oy); o.z = f2bf(oz); o.w = f2bf(ow);
    *(ushort4*)(out + (size_t)wid * 256 + lane * 4) = o;
}

// ------------------------- GAT aggregation, H=1 (single pass, no exp) -----

__global__ void gat_agg_h1(const unsigned short* __restrict__ Hpre,
                           const float2* __restrict__ eA, const float2* __restrict__ eB,
                           const int* __restrict__ rowptr, const int* __restrict__ csr_src,
                           const float* __restrict__ bias, unsigned short* __restrict__ out,
                           int N) {
    int wid = (blockIdx.x * blockDim.x + threadIdx.x) >> 6;
    int lane = threadIdx.x & 63;
    if (wid >= N) return;
    const int rs = rowptr[wid], re = rowptr[wid + 1];
    const int half = lane >> 5, c = lane & 31;
    const float2 Bv = eB[wid];

    float z = 0.f;
    float4 a0 = {0.f, 0.f, 0.f, 0.f}, a1 = {0.f, 0.f, 0.f, 0.f};
    float4 a2 = {0.f, 0.f, 0.f, 0.f}, a3 = {0.f, 0.f, 0.f, 0.f};
    int i = rs + half;
    for (; i + 6 < re; i += 8) {
        int s0 = csr_src[i], s1 = csr_src[i + 2], s2 = csr_src[i + 4], s3 = csr_src[i + 6];
        float2 A0 = eA[s0], A1 = eA[s1], A2 = eA[s2], A3 = eA[s3];
        float p0 = A0.x * Bv.x, p1 = A1.x * Bv.x, p2 = A2.x * Bv.x, p3 = A3.x * Bv.x;
        float w0 = (p0 > 1.f) ? p0 : A0.y * Bv.y;
        float w1 = (p1 > 1.f) ? p1 : A1.y * Bv.y;
        float w2 = (p2 > 1.f) ? p2 : A2.y * Bv.y;
        float w3 = (p3 > 1.f) ? p3 : A3.y * Bv.y;
        z += (w0 + w1) + (w2 + w3);
        ushort4 u0 = *(const ushort4*)(Hpre + (size_t)s0 * 128 + c * 4);
        ushort4 u1 = *(const ushort4*)(Hpre + (size_t)s1 * 128 + c * 4);
        ushort4 u2 = *(const ushort4*)(Hpre + (size_t)s2 * 128 + c * 4);
        ushort4 u3 = *(const ushort4*)(Hpre + (size_t)s3 * 128 + c * 4);
        a0.x += w0 * bf2f(u0.x); a0.y += w0 * bf2f(u0.y);
        a0.z += w0 * bf2f(u0.z); a0.w += w0 * bf2f(u0.w);
        a1.x += w1 * bf2f(u1.x); a1.y += w1 * bf2f(u1.y);
        a1.z += w1 * bf2f(u1.z); a1.w += w1 * bf2f(u1.w);
        a2.x += w2 * bf2f(u2.x); a2.y += w2 * bf2f(u2.y);
        a2.z += w2 * bf2f(u2.z); a2.w += w2 * bf2f(u2.w);
        a3.x += w3 * bf2f(u3.x); a3.y += w3 * bf2f(u3.y);
        a3.z += w3 * bf2f(u3.z); a3.w += w3 * bf2f(u3.w);
    }
    for (; i < re; i += 2) {
        int s0 = csr_src[i];
        float2 A0 = eA[s0];
        float p0 = A0.x * Bv.x;
        float w0 = (p0 > 1.f) ? p0 : A0.y * Bv.y;
        z += w0;
        ushort4 u0 = *(const ushort4*)(Hpre + (size_t)s0 * 128 + c * 4);
        a0.x += w0 * bf2f(u0.x); a0.y += w0 * bf2f(u0.y);
        a0.z += w0 * bf2f(u0.z); a0.w += w0 * bf2f(u0.w);
    }
    z += __shfl_xor(z, 32, 64);
    const float rz = 1.f / (z + 1e-16f);

    float ox = a0.x + a1.x + a2.x + a3.x;
    float oy = a0.y + a1.y + a2.y + a3.y;
    float oz = a0.z + a1.z + a2.z + a3.z;
    float ow = a0.w + a1.w + a2.w + a3.w;
    ox += __shfl_xor(ox, 32, 64);
    oy += __shfl_xor(oy, 32, 64);
    oz += __shfl_xor(oz, 32, 64);
    ow += __shfl_xor(ow, 32, 64);
    if (lane < 32) {
        float4 bv = ((const float4*)bias)[c];
        ox = ox * rz + bv.x; oy = oy * rz + bv.y; oz = oz * rz + bv.z; ow = ow * rz + bv.w;
        ox = (ox > 0.f) ? ox : __expf(ox) - 1.f;
        oy = (oy > 0.f) ? oy : __expf(oy) - 1.f;
        oz = (oz > 0.f) ? oz : __expf(oz) - 1.f;
        ow = (ow > 0.f) ? ow : __expf(ow) - 1.f;
        ushort4 o;
        o.x = f2bf(ox); o.y = f2bf(oy); o.z = f2bf(oz); o.w = f2bf(ow);
        *(ushort4*)(out + (size_t)wid * 128 + c * 4) = o;
    }
}

// ------------------------- global mean pool (chunk-parallel) --------------

#define PCHUNK 256

__global__ __launch_bounds__(256) void pool_partial(const unsigned short* __restrict__ h2,
                                                    const int* __restrict__ batch,
                                                    float* __restrict__ xsum,
                                                    int* __restrict__ cnt, int N) {
    const int base = blockIdx.x * PCHUNK;
    const int rg = threadIdx.x >> 6;
    const int c2 = threadIdx.x & 63;
    float ax = 0.f, ay = 0.f;
    int gcur = -1, run = 0;
    for (int r = rg; r < PCHUNK; r += 4) {
        int i = base + r;
        if (i >= N) break;
        int g = batch[i];
        if (g != gcur) {
            if (gcur >= 0) {
                atomicAdd(&xsum[gcur * 128 + c2 * 2 + 0], ax);
                atomicAdd(&xsum[gcur * 128 + c2 * 2 + 1], ay);
                if (c2 == 0) atomicAdd(&cnt[gcur], run);
            }
            gcur = g; ax = 0.f; ay = 0.f; run = 0;
        }
        ushort2 u = *(const ushort2*)(h2 + (size_t)i * 128 + c2 * 2);
        ax += bf2f(u.x); ay += bf2f(u.y);
        run += 1;
    }
    if (gcur >= 0) {
        atomicAdd(&xsum[gcur * 128 + c2 * 2 + 0], ax);
        atomicAdd(&xsum[gcur * 128 + c2 * 2 + 1], ay);
        if (c2 == 0) atomicAdd(&cnt[gcur], run);
    }
}

// ------------------------- policy / value heads ---------------------------

__global__ void head_kernel(const float* __restrict__ xsum, const int* __restrict__ cnt,
                            const float* __restrict__ Wp, const float* __restrict__ bp,
                            const float* __restrict__ Wv, const float* __restrict__ bv,
                            float* __restrict__ out) {
    int g = blockIdx.x, t = threadIdx.x;  // 64 threads
    __shared__ float p[128];
    float inv = 1.f / fmaxf((float)cnt[g], 1.f);
    p[t] = xsum[g * 128 + t] * inv;
    p[t + 64] = xsum[g * 128 + t + 64] * inv;
    __syncthreads();
    if (t < 32) {
        float acc = bp[t];
        for (int k = 0; k < 128; ++k) acc += p[k] * Wp[k * 32 + t];
        out[g * 32 + t] = acc;
    } else if (t == 32) {
        float acc = bv[0];
        for (int k = 0; k < 128; ++k) acc += p[k] * Wv[k];
        out[64 * 32 + g] = acc;
    }
}

// ---------------------------------------------------------------------------

extern "C" void kernel_launch(void* const* d_in, const int* in_sizes, int n_in,
                              void* d_out, int out_size, void* d_ws, size_t ws_size,
                              hipStream_t stream) {
    const float* x      = (const float*)d_in[0];
    const int*   ei     = (const int*)d_in[1];
    const int*   batch  = (const int*)d_in[2];
    const float* W1     = (const float*)d_in[3];
    const float* a_src1 = (const float*)d_in[4];
    const float* a_dst1 = (const float*)d_in[5];
    const float* b1     = (const float*)d_in[6];
    const float* W2     = (const float*)d_in[7];
    const float* a_src2 = (const float*)d_in[8];
    const float* a_dst2 = (const float*)d_in[9];
    const float* b2     = (const float*)d_in[10];
    const float* Wp     = (const float*)d_in[11];
    const float* bp     = (const float*)d_in[12];
    const float* Wv     = (const float*)d_in[13];
    const float* bv     = (const float*)d_in[14];

    const int N  = in_sizes[0] / 128;
    const int E  = in_sizes[1] / 2;
    const int ET = E + N;
    const int TILES = (N + 1023) / 1024;
    const int NPAD = ((N + 63) / 64) * 64;
    const int NBLK = NPAD / 64;
    const int SBLK = (ET + 255) / 256;
    const int PBLK = (N + PCHUNK - 1) / PCHUNK;

    char* ws = (char*)d_ws;
    size_t off = 0;
    auto alloc = [&](size_t bytes) -> void* {
        void* p = ws + off;
        off = (off + bytes + 255) & ~(size_t)255;
        return p;
    };
    unsigned short* h1pre = (unsigned short*)alloc((size_t)NPAD * 256 * 2);  // reused as h2pre
    unsigned short* h1bf  = (unsigned short*)alloc((size_t)NPAD * 256 * 2);
    unsigned short* h2bf  = (unsigned short*)alloc((size_t)N * 128 * 2);
    unsigned short* w1sw  = (unsigned short*)alloc((size_t)128 * 256 * 2);
    unsigned short* w2sw  = (unsigned short*)alloc((size_t)256 * 128 * 2);
    float2* eA1 = (float2*)alloc((size_t)N * 2 * 8);
    float2* eB1 = (float2*)alloc((size_t)N * 2 * 8);
    float2* eA2 = (float2*)alloc((size_t)N * 8);
    float2* eB2 = (float2*)alloc((size_t)N * 8);
    // contiguous zero region: deg | xsum | cnt
    const int ZINTS = N + 64 * 128 + 64;
    int*   zbase  = (int*)alloc(((size_t)ZINTS + 8) * 4);
    int*   deg    = zbase;
    float* xsum   = (float*)(zbase + N);
    int*   cnt    = (int*)(xsum + 64 * 128);
    int*   rowptr = (int*)alloc((size_t)(N + 1) * 4);
    int*   cursor = (int*)alloc((size_t)N * 4);
    int*   csrsrc = (int*)alloc((size_t)ET * 4);
    int*   tsum   = (int*)alloc(64 * 4);
    unsigned short* h2pre = h1pre;  // h1pre dead after layer-1 agg
    const int zn4 = (ZINTS + 3) / 4;

    // --- init: zero (deg/xsum/cnt) + both weight swizzles, one launch ---
    init_kernel<<<32 + (zn4 + 255) / 256, 256, 0, stream>>>(W1, W2, w1sw, w2sw, zbase, zn4);

    // --- CSR build ---
    degree_kernel<<<(ET + 255) / 256, 256, 0, stream>>>(ei, deg, E, N);
    scan_tiles<<<TILES, 256, 0, stream>>>(deg, tsum, N);
    scan_add<<<TILES, 256, 0, stream>>>(deg, tsum, rowptr, cursor, N, TILES);

    // --- scatter ∥ gemm1 (interleaved roles, one kernel) ---
    scatter_gemm1<<<NBLK + SBLK, 256, 0, stream>>>(ei, cursor, csrsrc, x, w1sw,
                                                   a_src1, a_dst1, eA1, eB1, h1pre,
                                                   E, N, NBLK);

    // --- layer 1 aggregation ---
    gat_agg_h2<<<(N + 3) / 4, 256, 0, stream>>>(h1pre, eA1, eB1, rowptr, csrsrc, b1,
                                                h1bf, N);

    // --- layer 2 ---
    gemm_mfma<256, 128, 1, false><<<NBLK, 256, 0, stream>>>(h1bf, w2sw, a_src2, a_dst2,
                                                            eA2, eB2, h2pre, N);
    gat_agg_h1<<<(N + 3) / 4, 256, 0, stream>>>(h2pre, eA2, eB2, rowptr, csrsrc, b2,
                                                h2bf, N);

    // --- pool + heads ---
    pool_partial<<<PBLK, 256, 0, stream>>>(h2bf, batch, xsum, cnt, N);
    head_kernel<<<64, 64, 0, stream>>>(xsum, cnt, Wp, bp, Wv, bv, (float*)d_out);
}

// Round 13
// 387.631 us; speedup vs baseline: 1.0318x; 1.0318x over previous
//
#include <hip/hip_runtime.h>
#include <hip/hip_bf16.h>
#include <cstdint>

// ---------------------------------------------------------------------------
// GraphRLAgent: 2-layer GAT (heads=2 then 1) + global mean pool + 2 heads.
// Round 13:
//  - UN-fuse scatter∥gemm1 (fused kernel forced 80 VGPR on scatter blocks,
//    occupancy 63%->14% on the latency-bound path: 110us vs 94 serial).
//  - dst-range-partitioned scatter (8 ranges): writes confined to ~425KB
//    L2-resident window per range -> HBM write-allocate 55MB -> ~6MB.
//  - keeps separable-exp edge weights + LDS-reduction GEMM epilogue.
// ---------------------------------------------------------------------------

typedef __attribute__((ext_vector_type(8))) short bf16x8;
typedef __attribute__((ext_vector_type(4))) float f32x4;

#define RANGES 8

__device__ __forceinline__ unsigned short f2bf(float f) {
    union { float f; uint32_t u; } c; c.f = f;
    uint32_t u = c.u;
    return (unsigned short)((u + 0x7fffu + ((u >> 16) & 1u)) >> 16);
}

__device__ __forceinline__ float bf2f(unsigned short u) {
    union { uint32_t u; float f; } c; c.u = ((uint32_t)u) << 16;
    return c.f;
}

// ------------------------- B swizzle body ---------------------------------

template <int K, int FOUT>
__device__ __forceinline__ void swizzle_body(const float* __restrict__ W,
                                             unsigned short* __restrict__ Bsw, int tid) {
    constexpr int CPW = FOUT / 4, NCT = CPW / 16, KST = K / 32;
    if (tid >= K * FOUT / 8) return;
    int lane = tid & 63;
    int rest = tid >> 6;
    int t = rest % KST; rest /= KST;
    int c = rest % NCT; rest /= NCT;
    int cg_ = rest;
    int quad = lane >> 4, lo = lane & 15;
    int col = cg_ * CPW + c * 16 + lo;
    unsigned short v[8];
#pragma unroll
    for (int j = 0; j < 8; ++j)
        v[j] = f2bf(W[(t * 32 + quad * 8 + j) * FOUT + col]);
    ushort4* dst = (ushort4*)(Bsw + (size_t)tid * 8);
    ushort4 o0, o1;
    o0.x = v[0]; o0.y = v[1]; o0.z = v[2]; o0.w = v[3];
    o1.x = v[4]; o1.y = v[5]; o1.z = v[6]; o1.w = v[7];
    dst[0] = o0; dst[1] = o1;
}

// ------------------------- init: zero + swizzle ---------------------------

__global__ void init_kernel(const float* __restrict__ W1, const float* __restrict__ W2,
                            unsigned short* __restrict__ B1, unsigned short* __restrict__ B2,
                            int* __restrict__ zbase, int zn4) {
    int b = blockIdx.x;
    if (b < 16)       swizzle_body<128, 256>(W1, B1, b * 256 + threadIdx.x);
    else if (b < 32)  swizzle_body<256, 128>(W2, B2, (b - 16) * 256 + threadIdx.x);
    else {
        int i = (b - 32) * 256 + threadIdx.x;
        if (i < zn4) ((int4*)zbase)[i] = make_int4(0, 0, 0, 0);
    }
}

// ------------------------- CSR construction -------------------------------

__global__ void degree_kernel(const int* __restrict__ ei, int* __restrict__ deg,
                              int E, int N) {
    int i = blockIdx.x * blockDim.x + threadIdx.x;
    if (i >= E + N) return;
    int dst = (i < E) ? ei[E + i] : (i - E);
    atomicAdd(&deg[dst], 1);
}

__global__ __launch_bounds__(256) void scan_tiles(int* __restrict__ deg,
                                                  int* __restrict__ tsum, int N) {
    __shared__ int buf[256];
    const int t = threadIdx.x;
    const int base = blockIdx.x * 1024 + t * 4;
    int v[4]; int s = 0;
#pragma unroll
    for (int k = 0; k < 4; ++k) { v[k] = (base + k < N) ? deg[base + k] : 0; s += v[k]; }
    buf[t] = s;
    __syncthreads();
#pragma unroll
    for (int off = 1; off < 256; off <<= 1) {
        int x = (t >= off) ? buf[t - off] : 0;
        __syncthreads();
        buf[t] += x;
        __syncthreads();
    }
    int run = buf[t] - s;
#pragma unroll
    for (int k = 0; k < 4; ++k) {
        if (base + k < N) deg[base + k] = run;
        run += v[k];
    }
    if (t == 255) tsum[blockIdx.x] = buf[255];
}

__global__ __launch_bounds__(256) void scan_add(const int* __restrict__ partial,
                                                const int* __restrict__ tsum,
                                                int* __restrict__ rowptr,
                                                int* __restrict__ cursor, int N, int T) {
    __shared__ int s_toff;
    const int tile = blockIdx.x;
    if (threadIdx.x < 64) {
        int t = threadIdx.x;
        int v = (t < T) ? tsum[t] : 0;
#pragma unroll
        for (int off = 1; off < 64; off <<= 1) {
            int x = __shfl_up(v, off, 64);
            if (t >= off) v += x;
        }
        int toff = (tile == 0) ? 0 : __shfl(v, tile - 1, 64);
        if (t == 0) s_toff = toff;
        if (tile == 0 && t == 63) rowptr[N] = v;
    }
    __syncthreads();
    const int toff = s_toff;
    int i = tile * 1024 + threadIdx.x * 4;
#pragma unroll
    for (int k = 0; k < 4; ++k) {
        if (i + k < N) {
            int r = partial[i + k] + toff;
            rowptr[i + k] = r;
            cursor[i + k] = r;
        }
    }
}

// dst-range-partitioned scatter: block (r, chunk) reads edge chunk but only
// commits edges with dst in range r -> csrsrc writes stay in an L2-resident
// ~425KB window per range (write-allocate traffic collapses).
__global__ void scatter_kernel(const int* __restrict__ ei, int* __restrict__ cursor,
                               int* __restrict__ csr_src, int E, int N,
                               int SBLK, int RSIZE) {
    int r = blockIdx.x / SBLK;
    int i = (blockIdx.x % SBLK) * 256 + threadIdx.x;
    if (i >= E + N) return;
    int src, dst;
    if (i < E) { src = ei[i]; dst = ei[E + i]; }
    else       { src = dst = i - E; }
    int lo = r * RSIZE;
    if (dst < lo || dst >= lo + RSIZE) return;
    int pos = atomicAdd(&cursor[dst], 1);
    csr_src[pos] = src;
}

// ------------------------- bf16 MFMA GEMM + exp-coef epilogue -------------

template <int K, int FOUT, int H, bool A32>
__global__ __launch_bounds__(256) void gemm_mfma(const void* __restrict__ Av,
                                                 const unsigned short* __restrict__ Bsw,
                                                 const float* __restrict__ a_src,
                                                 const float* __restrict__ a_dst,
                                                 float2* __restrict__ eA, float2* __restrict__ eB,
                                                 unsigned short* __restrict__ C, int N) {
    constexpr int CPW = FOUT / 4;
    constexpr int NCT = CPW / 16;
    constexpr int KST = K / 32;
    const int tid = threadIdx.x;
    const int wave = tid >> 6, lane = tid & 63;
    const int quad = lane >> 4, lo = lane & 15;
    const int n0 = blockIdx.x * 64;
    const int c0 = wave * CPW;
    __shared__ float lds_ps[4][64];
    __shared__ float lds_pd[4][64];

    bf16x8 bf[NCT][KST];
    {
        const bf16x8* Bp = (const bf16x8*)Bsw;
#pragma unroll
        for (int c = 0; c < NCT; ++c)
#pragma unroll
            for (int t = 0; t < KST; ++t)
                bf[c][t] = Bp[((wave * NCT + c) * KST + t) * 64 + lane];
    }

    f32x4 acc[4][NCT];
#pragma unroll
    for (int r = 0; r < 4; ++r)
#pragma unroll
        for (int c = 0; c < NCT; ++c) acc[r][c] = (f32x4){0.f, 0.f, 0.f, 0.f};

#pragma unroll
    for (int r = 0; r < 4; ++r) {
        const int arow = n0 + r * 16 + lo;
        if (A32) {
            const size_t rclamp = (arow < N) ? (size_t)arow : 0;
            const float* Ar = (const float*)Av + rclamp * K + quad * 8;
            const bool valid = arow < N;
#pragma unroll
            for (int t = 0; t < KST; ++t) {
                bf16x8 af;
                if (valid) {
                    float4 v0 = *(const float4*)(Ar + t * 32);
                    float4 v1 = *(const float4*)(Ar + t * 32 + 4);
                    af[0] = (short)f2bf(v0.x); af[1] = (short)f2bf(v0.y);
                    af[2] = (short)f2bf(v0.z); af[3] = (short)f2bf(v0.w);
                    af[4] = (short)f2bf(v1.x); af[5] = (short)f2bf(v1.y);
                    af[6] = (short)f2bf(v1.z); af[7] = (short)f2bf(v1.w);
                } else {
                    af = (bf16x8){0, 0, 0, 0, 0, 0, 0, 0};
                }
#pragma unroll
                for (int c = 0; c < NCT; ++c)
                    acc[r][c] = __builtin_amdgcn_mfma_f32_16x16x32_bf16(af, bf[c][t], acc[r][c],
                                                                       0, 0, 0);
            }
        } else {
            const unsigned short* Ar = (const unsigned short*)Av + (size_t)arow * K + quad * 8;
#pragma unroll
            for (int t = 0; t < KST; ++t) {
                bf16x8 af = *(const bf16x8*)(Ar + t * 32);
#pragma unroll
                for (int c = 0; c < NCT; ++c)
                    acc[r][c] = __builtin_amdgcn_mfma_f32_16x16x32_bf16(af, bf[c][t], acc[r][c],
                                                                       0, 0, 0);
            }
        }
    }

    // C/D layout: col = lane&15, row = quad*4 + j
#pragma unroll
    for (int r = 0; r < 4; ++r) {
        int row = n0 + r * 16 + quad * 4;
#pragma unroll
        for (int c = 0; c < NCT; ++c) {
            int col = c0 + c * 16 + lo;
#pragma unroll
            for (int j = 0; j < 4; ++j)
                if (row + j < N) C[(size_t)(row + j) * FOUT + col] = f2bf(acc[r][c][j]);
        }
    }

    // attention-coef partial dots -> LDS -> exp pairs (no atomics)
    float asv[NCT], adv[NCT];
#pragma unroll
    for (int c = 0; c < NCT; ++c) {
        int col = c0 + c * 16 + lo;
        asv[c] = a_src[col];
        adv[c] = a_dst[col];
    }
#pragma unroll
    for (int r = 0; r < 4; ++r) {
#pragma unroll
        for (int j = 0; j < 4; ++j) {
            float ps = 0.f, pd = 0.f;
#pragma unroll
            for (int c = 0; c < NCT; ++c) { ps += acc[r][c][j] * asv[c]; pd += acc[r][c][j] * adv[c]; }
#pragma unroll
            for (int off = 1; off <= 8; off <<= 1) {
                ps += __shfl_xor(ps, off, 64);
                pd += __shfl_xor(pd, off, 64);
            }
            if (lo == 0) {
                int row_l = r * 16 + quad * 4 + j;
                lds_ps[wave][row_l] = ps;
                lds_pd[wave][row_l] = pd;
            }
        }
    }
    __syncthreads();
    if (tid < 64 * H) {
        int row = tid & 63, h = tid >> 6;
        int n = n0 + row;
        if (n < N) {
            float ps, pd;
            if (H == 2) {
                ps = lds_ps[2 * h][row] + lds_ps[2 * h + 1][row];
                pd = lds_pd[2 * h][row] + lds_pd[2 * h + 1][row];
            } else {
                ps = lds_ps[0][row] + lds_ps[1][row] + lds_ps[2][row] + lds_ps[3][row];
                pd = lds_pd[0][row] + lds_pd[1][row] + lds_pd[2][row] + lds_pd[3][row];
            }
            eA[n * H + h] = make_float2(__expf(ps), __expf(0.2f * ps));
            eB[n * H + h] = make_float2(__expf(pd), __expf(0.2f * pd));
        }
    }
}

// ------------------------- GAT aggregation, H=2 (single pass, no exp) -----

__global__ void gat_agg_h2(const unsigned short* __restrict__ Hpre,
                           const float2* __restrict__ eA, const float2* __restrict__ eB,
                           const int* __restrict__ rowptr, const int* __restrict__ csr_src,
                           const float* __restrict__ bias, unsigned short* __restrict__ out,
                           int N) {
    int wid = (blockIdx.x * blockDim.x + threadIdx.x) >> 6;
    int lane = threadIdx.x & 63;
    if (wid >= N) return;
    const int rs = rowptr[wid], re = rowptr[wid + 1];
    const int h = lane >> 5;
    const float2 Bv = eB[wid * 2 + h];

    float z = 0.f;
    float4 a0 = {0.f, 0.f, 0.f, 0.f}, a1 = {0.f, 0.f, 0.f, 0.f};
    float4 a2 = {0.f, 0.f, 0.f, 0.f}, a3 = {0.f, 0.f, 0.f, 0.f};
    int i = rs;
    for (; i + 4 <= re; i += 4) {
        int s0 = csr_src[i], s1 = csr_src[i + 1], s2 = csr_src[i + 2], s3 = csr_src[i + 3];
        float2 A0 = eA[s0 * 2 + h], A1 = eA[s1 * 2 + h];
        float2 A2 = eA[s2 * 2 + h], A3 = eA[s3 * 2 + h];
        float p0 = A0.x * Bv.x, p1 = A1.x * Bv.x, p2 = A2.x * Bv.x, p3 = A3.x * Bv.x;
        float w0 = (p0 > 1.f) ? p0 : A0.y * Bv.y;
        float w1 = (p1 > 1.f) ? p1 : A1.y * Bv.y;
        float w2 = (p2 > 1.f) ? p2 : A2.y * Bv.y;
        float w3 = (p3 > 1.f) ? p3 : A3.y * Bv.y;
        z += (w0 + w1) + (w2 + w3);
        ushort4 u0 = *(const ushort4*)(Hpre + (size_t)s0 * 256 + lane * 4);
        ushort4 u1 = *(const ushort4*)(Hpre + (size_t)s1 * 256 + lane * 4);
        ushort4 u2 = *(const ushort4*)(Hpre + (size_t)s2 * 256 + lane * 4);
        ushort4 u3 = *(const ushort4*)(Hpre + (size_t)s3 * 256 + lane * 4);
        a0.x += w0 * bf2f(u0.x); a0.y += w0 * bf2f(u0.y);
        a0.z += w0 * bf2f(u0.z); a0.w += w0 * bf2f(u0.w);
        a1.x += w1 * bf2f(u1.x); a1.y += w1 * bf2f(u1.y);
        a1.z += w1 * bf2f(u1.z); a1.w += w1 * bf2f(u1.w);
        a2.x += w2 * bf2f(u2.x); a2.y += w2 * bf2f(u2.y);
        a2.z += w2 * bf2f(u2.z); a2.w += w2 * bf2f(u2.w);
        a3.x += w3 * bf2f(u3.x); a3.y += w3 * bf2f(u3.y);
        a3.z += w3 * bf2f(u3.z); a3.w += w3 * bf2f(u3.w);
    }
    for (; i < re; ++i) {
        int s0 = csr_src[i];
        float2 A0 = eA[s0 * 2 + h];
        float p0 = A0.x * Bv.x;
        float w0 = (p0 > 1.f) ? p0 : A0.y * Bv.y;
        z += w0;
        ushort4 u0 = *(const ushort4*)(Hpre + (size_t)s0 * 256 + lane * 4);
        a0.x += w0 * bf2f(u0.x); a0.y += w0 * bf2f(u0.y);
        a0.z += w0 * bf2f(u0.z); a0.w += w0 * bf2f(u0.w);
    }
    const float rz = 1.f / (z + 1e-16f);
    float4 bv = ((const float4*)bias)[lane];
    float ox = (a0.x + a1.x + a2.x + a3.x) * rz + bv.x;
    float oy = (a0.y + a1.y + a2.y + a3.y) * rz + bv.y;
    float oz = (a0.z + a1.z + a2.z + a3.z) * rz + bv.z;
    float ow = (a0.w + a1.w + a2.w + a3.w) * rz + bv.w;
    ox = (ox > 0.f) ? ox : __expf(ox) - 1.f;
    oy = (oy > 0.f) ? oy : __expf(oy) - 1.f;
    oz = (oz > 0.f) ? oz : __expf(oz) - 1.f;
    ow = (ow > 0.f) ? ow : __expf(ow) - 1.f;
    ushort4 o;
    o.x = f2bf(ox); o.y = f2bf(oy); o.z = f2bf(oz); o.w = f2bf(ow);
    *(ushort4*)(out + (size_t)wid * 256 + lane * 4) = o;
}

// ------------------------- GAT aggregation, H=1 (single pass, no exp) -----

__global__ void gat_agg_h1(const unsigned short* __restrict__ Hpre,
                           const float2* __restrict__ eA, const float2* __restrict__ eB,
                           const int* __restrict__ rowptr, const int* __restrict__ csr_src,
                           const float* __restrict__ bias, unsigned short* __restrict__ out,
                           int N) {
    int wid = (blockIdx.x * blockDim.x + threadIdx.x) >> 6;
    int lane = threadIdx.x & 63;
    if (wid >= N) return;
    const int rs = rowptr[wid], re = rowptr[wid + 1];
    const int half = lane >> 5, c = lane & 31;
    const float2 Bv = eB[wid];

    float z = 0.f;
    float4 a0 = {0.f, 0.f, 0.f, 0.f}, a1 = {0.f, 0.f, 0.f, 0.f};
    float4 a2 = {0.f, 0.f, 0.f, 0.f}, a3 = {0.f, 0.f, 0.f, 0.f};
    int i = rs + half;
    for (; i + 6 < re; i += 8) {
        int s0 = csr_src[i], s1 = csr_src[i + 2], s2 = csr_src[i + 4], s3 = csr_src[i + 6];
        float2 A0 = eA[s0], A1 = eA[s1], A2 = eA[s2], A3 = eA[s3];
        float p0 = A0.x * Bv.x, p1 = A1.x * Bv.x, p2 = A2.x * Bv.x, p3 = A3.x * Bv.x;
        float w0 = (p0 > 1.f) ? p0 : A0.y * Bv.y;
        float w1 = (p1 > 1.f) ? p1 : A1.y * Bv.y;
        float w2 = (p2 > 1.f) ? p2 : A2.y * Bv.y;
        float w3 = (p3 > 1.f) ? p3 : A3.y * Bv.y;
        z += (w0 + w1) + (w2 + w3);
        ushort4 u0 = *(const ushort4*)(Hpre + (size_t)s0 * 128 + c * 4);
        ushort4 u1 = *(const ushort4*)(Hpre + (size_t)s1 * 128 + c * 4);
        ushort4 u2 = *(const ushort4*)(Hpre + (size_t)s2 * 128 + c * 4);
        ushort4 u3 = *(const ushort4*)(Hpre + (size_t)s3 * 128 + c * 4);
        a0.x += w0 * bf2f(u0.x); a0.y += w0 * bf2f(u0.y);
        a0.z += w0 * bf2f(u0.z); a0.w += w0 * bf2f(u0.w);
        a1.x += w1 * bf2f(u1.x); a1.y += w1 * bf2f(u1.y);
        a1.z += w1 * bf2f(u1.z); a1.w += w1 * bf2f(u1.w);
        a2.x += w2 * bf2f(u2.x); a2.y += w2 * bf2f(u2.y);
        a2.z += w2 * bf2f(u2.z); a2.w += w2 * bf2f(u2.w);
        a3.x += w3 * bf2f(u3.x); a3.y += w3 * bf2f(u3.y);
        a3.z += w3 * bf2f(u3.z); a3.w += w3 * bf2f(u3.w);
    }
    for (; i < re; i += 2) {
        int s0 = csr_src[i];
        float2 A0 = eA[s0];
        float p0 = A0.x * Bv.x;
        float w0 = (p0 > 1.f) ? p0 : A0.y * Bv.y;
        z += w0;
        ushort4 u0 = *(const ushort4*)(Hpre + (size_t)s0 * 128 + c * 4);
        a0.x += w0 * bf2f(u0.x); a0.y += w0 * bf2f(u0.y);
        a0.z += w0 * bf2f(u0.z); a0.w += w0 * bf2f(u0.w);
    }
    z += __shfl_xor(z, 32, 64);
    const float rz = 1.f / (z + 1e-16f);

    float ox = a0.x + a1.x + a2.x + a3.x;
    float oy = a0.y + a1.y + a2.y + a3.y;
    float oz = a0.z + a1.z + a2.z + a3.z;
    float ow = a0.w + a1.w + a2.w + a3.w;
    ox += __shfl_xor(ox, 32, 64);
    oy += __shfl_xor(oy, 32, 64);
    oz += __shfl_xor(oz, 32, 64);
    ow += __shfl_xor(ow, 32, 64);
    if (lane < 32) {
        float4 bv = ((const float4*)bias)[c];
        ox = ox * rz + bv.x; oy = oy * rz + bv.y; oz = oz * rz + bv.z; ow = ow * rz + bv.w;
        ox = (ox > 0.f) ? ox : __expf(ox) - 1.f;
        oy = (oy > 0.f) ? oy : __expf(oy) - 1.f;
        oz = (oz > 0.f) ? oz : __expf(oz) - 1.f;
        ow = (ow > 0.f) ? ow : __expf(ow) - 1.f;
        ushort4 o;
        o.x = f2bf(ox); o.y = f2bf(oy); o.z = f2bf(oz); o.w = f2bf(ow);
        *(ushort4*)(out + (size_t)wid * 128 + c * 4) = o;
    }
}

// ------------------------- global mean pool (chunk-parallel) --------------

#define PCHUNK 256

__global__ __launch_bounds__(256) void pool_partial(const unsigned short* __restrict__ h2,
                                                    const int* __restrict__ batch,
                                                    float* __restrict__ xsum,
                                                    int* __restrict__ cnt, int N) {
    const int base = blockIdx.x * PCHUNK;
    const int rg = threadIdx.x >> 6;
    const int c2 = threadIdx.x & 63;
    float ax = 0.f, ay = 0.f;
    int gcur = -1, run = 0;
    for (int r = rg; r < PCHUNK; r += 4) {
        int i = base + r;
        if (i >= N) break;
        int g = batch[i];
        if (g != gcur) {
            if (gcur >= 0) {
                atomicAdd(&xsum[gcur * 128 + c2 * 2 + 0], ax);
                atomicAdd(&xsum[gcur * 128 + c2 * 2 + 1], ay);
                if (c2 == 0) atomicAdd(&cnt[gcur], run);
            }
            gcur = g; ax = 0.f; ay = 0.f; run = 0;
        }
        ushort2 u = *(const ushort2*)(h2 + (size_t)i * 128 + c2 * 2);
        ax += bf2f(u.x); ay += bf2f(u.y);
        run += 1;
    }
    if (gcur >= 0) {
        atomicAdd(&xsum[gcur * 128 + c2 * 2 + 0], ax);
        atomicAdd(&xsum[gcur * 128 + c2 * 2 + 1], ay);
        if (c2 == 0) atomicAdd(&cnt[gcur], run);
    }
}

// ------------------------- policy / value heads ---------------------------

__global__ void head_kernel(const float* __restrict__ xsum, const int* __restrict__ cnt,
                            const float* __restrict__ Wp, const float* __restrict__ bp,
                            const float* __restrict__ Wv, const float* __restrict__ bv,
                            float* __restrict__ out) {
    int g = blockIdx.x, t = threadIdx.x;  // 64 threads
    __shared__ float p[128];
    float inv = 1.f / fmaxf((float)cnt[g], 1.f);
    p[t] = xsum[g * 128 + t] * inv;
    p[t + 64] = xsum[g * 128 + t + 64] * inv;
    __syncthreads();
    if (t < 32) {
        float acc = bp[t];
        for (int k = 0; k < 128; ++k) acc += p[k] * Wp[k * 32 + t];
        out[g * 32 + t] = acc;
    } else if (t == 32) {
        float acc = bv[0];
        for (int k = 0; k < 128; ++k) acc += p[k] * Wv[k];
        out[64 * 32 + g] = acc;
    }
}

// ---------------------------------------------------------------------------

extern "C" void kernel_launch(void* const* d_in, const int* in_sizes, int n_in,
                              void* d_out, int out_size, void* d_ws, size_t ws_size,
                              hipStream_t stream) {
    const float* x      = (const float*)d_in[0];
    const int*   ei     = (const int*)d_in[1];
    const int*   batch  = (const int*)d_in[2];
    const float* W1     = (const float*)d_in[3];
    const float* a_src1 = (const float*)d_in[4];
    const float* a_dst1 = (const float*)d_in[5];
    const float* b1     = (const float*)d_in[6];
    const float* W2     = (const float*)d_in[7];
    const float* a_src2 = (const float*)d_in[8];
    const float* a_dst2 = (const float*)d_in[9];
    const float* b2     = (const float*)d_in[10];
    const float* Wp     = (const float*)d_in[11];
    const float* bp     = (const float*)d_in[12];
    const float* Wv     = (const float*)d_in[13];
    const float* bv     = (const float*)d_in[14];

    const int N  = in_sizes[0] / 128;
    const int E  = in_sizes[1] / 2;
    const int ET = E + N;
    const int TILES = (N + 1023) / 1024;
    const int NPAD = ((N + 63) / 64) * 64;
    const int NBLK = NPAD / 64;
    const int SBLK = (ET + 255) / 256;
    const int RSIZE = (N + RANGES - 1) / RANGES;
    const int PBLK = (N + PCHUNK - 1) / PCHUNK;

    char* ws = (char*)d_ws;
    size_t off = 0;
    auto alloc = [&](size_t bytes) -> void* {
        void* p = ws + off;
        off = (off + bytes + 255) & ~(size_t)255;
        return p;
    };
    unsigned short* h1pre = (unsigned short*)alloc((size_t)NPAD * 256 * 2);  // reused as h2pre
    unsigned short* h1bf  = (unsigned short*)alloc((size_t)NPAD * 256 * 2);
    unsigned short* h2bf  = (unsigned short*)alloc((size_t)N * 128 * 2);
    unsigned short* w1sw  = (unsigned short*)alloc((size_t)128 * 256 * 2);
    unsigned short* w2sw  = (unsigned short*)alloc((size_t)256 * 128 * 2);
    float2* eA1 = (float2*)alloc((size_t)N * 2 * 8);
    float2* eB1 = (float2*)alloc((size_t)N * 2 * 8);
    float2* eA2 = (float2*)alloc((size_t)N * 8);
    float2* eB2 = (float2*)alloc((size_t)N * 8);
    // contiguous zero region: deg | xsum | cnt
    const int ZINTS = N + 64 * 128 + 64;
    int*   zbase  = (int*)alloc(((size_t)ZINTS + 8) * 4);
    int*   deg    = zbase;
    float* xsum   = (float*)(zbase + N);
    int*   cnt    = (int*)(xsum + 64 * 128);
    int*   rowptr = (int*)alloc((size_t)(N + 1) * 4);
    int*   cursor = (int*)alloc((size_t)N * 4);
    int*   csrsrc = (int*)alloc((size_t)ET * 4);
    int*   tsum   = (int*)alloc(64 * 4);
    unsigned short* h2pre = h1pre;  // h1pre dead after layer-1 agg
    const int zn4 = (ZINTS + 3) / 4;

    // --- init: zero (deg/xsum/cnt) + both weight swizzles, one launch ---
    init_kernel<<<32 + (zn4 + 255) / 256, 256, 0, stream>>>(W1, W2, w1sw, w2sw, zbase, zn4);

    // --- CSR build ---
    degree_kernel<<<(ET + 255) / 256, 256, 0, stream>>>(ei, deg, E, N);
    scan_tiles<<<TILES, 256, 0, stream>>>(deg, tsum, N);
    scan_add<<<TILES, 256, 0, stream>>>(deg, tsum, rowptr, cursor, N, TILES);
    scatter_kernel<<<RANGES * SBLK, 256, 0, stream>>>(ei, cursor, csrsrc, E, N, SBLK, RSIZE);

    // --- layer 1: heads=2 (A = fp32 x, cast in-reg; eA1/eB1 fused) ---
    gemm_mfma<128, 256, 2, true><<<NBLK, 256, 0, stream>>>(x, w1sw, a_src1, a_dst1,
                                                           eA1, eB1, h1pre, N);
    gat_agg_h2<<<(N + 3) / 4, 256, 0, stream>>>(h1pre, eA1, eB1, rowptr, csrsrc, b1,
                                                h1bf, N);

    // --- layer 2: heads=1 ---
    gemm_mfma<256, 128, 1, false><<<NBLK, 256, 0, stream>>>(h1bf, w2sw, a_src2, a_dst2,
                                                            eA2, eB2, h2pre, N);
    gat_agg_h1<<<(N + 3) / 4, 256, 0, stream>>>(h2pre, eA2, eB2, rowptr, csrsrc, b2,
                                                h2bf, N);

    // --- pool + heads ---
    pool_partial<<<PBLK, 256, 0, stream>>>(h2bf, batch, xsum, cnt, N);
    head_kernel<<<64, 64, 0, stream>>>(xsum, cnt, Wp, bp, Wv, bv, (float*)d_out);
}

// Round 14
// 371.718 us; speedup vs baseline: 1.0760x; 1.0428x over previous
//
#include <hip/hip_runtime.h>
#include <hip/hip_bf16.h>
#include <cstdint>

// ---------------------------------------------------------------------------
// GraphRLAgent: 2-layer GAT (heads=2 then 1) + global mean pool + 2 heads.
// Round 14: revert edge weights to raw es/ed (4B gather) + in-loop exp —
// R13's float2 exp-pairs doubled the random gather bytes (74us vs 64.5; the
// exp was latency-hidden, the bytes were not). Keeps: LDS-reduction GEMM
// epilogue (no atomics/zeroing), dst-range scatter, fused init.
// ---------------------------------------------------------------------------

typedef __attribute__((ext_vector_type(8))) short bf16x8;
typedef __attribute__((ext_vector_type(4))) float f32x4;

#define RANGES 8

__device__ __forceinline__ unsigned short f2bf(float f) {
    union { float f; uint32_t u; } c; c.f = f;
    uint32_t u = c.u;
    return (unsigned short)((u + 0x7fffu + ((u >> 16) & 1u)) >> 16);
}

__device__ __forceinline__ float bf2f(unsigned short u) {
    union { uint32_t u; float f; } c; c.u = ((uint32_t)u) << 16;
    return c.f;
}

// ------------------------- B swizzle body ---------------------------------

template <int K, int FOUT>
__device__ __forceinline__ void swizzle_body(const float* __restrict__ W,
                                             unsigned short* __restrict__ Bsw, int tid) {
    constexpr int CPW = FOUT / 4, NCT = CPW / 16, KST = K / 32;
    if (tid >= K * FOUT / 8) return;
    int lane = tid & 63;
    int rest = tid >> 6;
    int t = rest % KST; rest /= KST;
    int c = rest % NCT; rest /= NCT;
    int cg_ = rest;
    int quad = lane >> 4, lo = lane & 15;
    int col = cg_ * CPW + c * 16 + lo;
    unsigned short v[8];
#pragma unroll
    for (int j = 0; j < 8; ++j)
        v[j] = f2bf(W[(t * 32 + quad * 8 + j) * FOUT + col]);
    ushort4* dst = (ushort4*)(Bsw + (size_t)tid * 8);
    ushort4 o0, o1;
    o0.x = v[0]; o0.y = v[1]; o0.z = v[2]; o0.w = v[3];
    o1.x = v[4]; o1.y = v[5]; o1.z = v[6]; o1.w = v[7];
    dst[0] = o0; dst[1] = o1;
}

// ------------------------- init: zero + swizzle ---------------------------

__global__ void init_kernel(const float* __restrict__ W1, const float* __restrict__ W2,
                            unsigned short* __restrict__ B1, unsigned short* __restrict__ B2,
                            int* __restrict__ zbase, int zn4) {
    int b = blockIdx.x;
    if (b < 16)       swizzle_body<128, 256>(W1, B1, b * 256 + threadIdx.x);
    else if (b < 32)  swizzle_body<256, 128>(W2, B2, (b - 16) * 256 + threadIdx.x);
    else {
        int i = (b - 32) * 256 + threadIdx.x;
        if (i < zn4) ((int4*)zbase)[i] = make_int4(0, 0, 0, 0);
    }
}

// ------------------------- CSR construction -------------------------------

__global__ void degree_kernel(const int* __restrict__ ei, int* __restrict__ deg,
                              int E, int N) {
    int i = blockIdx.x * blockDim.x + threadIdx.x;
    if (i >= E + N) return;
    int dst = (i < E) ? ei[E + i] : (i - E);
    atomicAdd(&deg[dst], 1);
}

__global__ __launch_bounds__(256) void scan_tiles(int* __restrict__ deg,
                                                  int* __restrict__ tsum, int N) {
    __shared__ int buf[256];
    const int t = threadIdx.x;
    const int base = blockIdx.x * 1024 + t * 4;
    int v[4]; int s = 0;
#pragma unroll
    for (int k = 0; k < 4; ++k) { v[k] = (base + k < N) ? deg[base + k] : 0; s += v[k]; }
    buf[t] = s;
    __syncthreads();
#pragma unroll
    for (int off = 1; off < 256; off <<= 1) {
        int x = (t >= off) ? buf[t - off] : 0;
        __syncthreads();
        buf[t] += x;
        __syncthreads();
    }
    int run = buf[t] - s;
#pragma unroll
    for (int k = 0; k < 4; ++k) {
        if (base + k < N) deg[base + k] = run;
        run += v[k];
    }
    if (t == 255) tsum[blockIdx.x] = buf[255];
}

__global__ __launch_bounds__(256) void scan_add(const int* __restrict__ partial,
                                                const int* __restrict__ tsum,
                                                int* __restrict__ rowptr,
                                                int* __restrict__ cursor, int N, int T) {
    __shared__ int s_toff;
    const int tile = blockIdx.x;
    if (threadIdx.x < 64) {
        int t = threadIdx.x;
        int v = (t < T) ? tsum[t] : 0;
#pragma unroll
        for (int off = 1; off < 64; off <<= 1) {
            int x = __shfl_up(v, off, 64);
            if (t >= off) v += x;
        }
        int toff = (tile == 0) ? 0 : __shfl(v, tile - 1, 64);
        if (t == 0) s_toff = toff;
        if (tile == 0 && t == 63) rowptr[N] = v;
    }
    __syncthreads();
    const int toff = s_toff;
    int i = tile * 1024 + threadIdx.x * 4;
#pragma unroll
    for (int k = 0; k < 4; ++k) {
        if (i + k < N) {
            int r = partial[i + k] + toff;
            rowptr[i + k] = r;
            cursor[i + k] = r;
        }
    }
}

// dst-range-partitioned scatter: writes confined to an L2-resident window.
__global__ void scatter_kernel(const int* __restrict__ ei, int* __restrict__ cursor,
                               int* __restrict__ csr_src, int E, int N,
                               int SBLK, int RSIZE) {
    int r = blockIdx.x / SBLK;
    int i = (blockIdx.x % SBLK) * 256 + threadIdx.x;
    if (i >= E + N) return;
    int src, dst;
    if (i < E) { src = ei[i]; dst = ei[E + i]; }
    else       { src = dst = i - E; }
    int lo = r * RSIZE;
    if (dst < lo || dst >= lo + RSIZE) return;
    int pos = atomicAdd(&cursor[dst], 1);
    csr_src[pos] = src;
}

// ------------------------- bf16 MFMA GEMM + attn-coef epilogue ------------
// C[N,FOUT](bf16) = A x B (fp32 acc). Epilogue: per-row dots with a_src/a_dst
// reduced via LDS (rows are block-exclusive) -> raw fp32 es/ed (no atomics).

template <int K, int FOUT, int H, bool A32>
__global__ __launch_bounds__(256) void gemm_mfma(const void* __restrict__ Av,
                                                 const unsigned short* __restrict__ Bsw,
                                                 const float* __restrict__ a_src,
                                                 const float* __restrict__ a_dst,
                                                 float* __restrict__ es, float* __restrict__ ed,
                                                 unsigned short* __restrict__ C, int N) {
    constexpr int CPW = FOUT / 4;
    constexpr int NCT = CPW / 16;
    constexpr int KST = K / 32;
    const int tid = threadIdx.x;
    const int wave = tid >> 6, lane = tid & 63;
    const int quad = lane >> 4, lo = lane & 15;
    const int n0 = blockIdx.x * 64;
    const int c0 = wave * CPW;
    __shared__ float lds_ps[4][64];
    __shared__ float lds_pd[4][64];

    bf16x8 bf[NCT][KST];
    {
        const bf16x8* Bp = (const bf16x8*)Bsw;
#pragma unroll
        for (int c = 0; c < NCT; ++c)
#pragma unroll
            for (int t = 0; t < KST; ++t)
                bf[c][t] = Bp[((wave * NCT + c) * KST + t) * 64 + lane];
    }

    f32x4 acc[4][NCT];
#pragma unroll
    for (int r = 0; r < 4; ++r)
#pragma unroll
        for (int c = 0; c < NCT; ++c) acc[r][c] = (f32x4){0.f, 0.f, 0.f, 0.f};

#pragma unroll
    for (int r = 0; r < 4; ++r) {
        const int arow = n0 + r * 16 + lo;
        if (A32) {
            const size_t rclamp = (arow < N) ? (size_t)arow : 0;
            const float* Ar = (const float*)Av + rclamp * K + quad * 8;
            const bool valid = arow < N;
#pragma unroll
            for (int t = 0; t < KST; ++t) {
                bf16x8 af;
                if (valid) {
                    float4 v0 = *(const float4*)(Ar + t * 32);
                    float4 v1 = *(const float4*)(Ar + t * 32 + 4);
                    af[0] = (short)f2bf(v0.x); af[1] = (short)f2bf(v0.y);
                    af[2] = (short)f2bf(v0.z); af[3] = (short)f2bf(v0.w);
                    af[4] = (short)f2bf(v1.x); af[5] = (short)f2bf(v1.y);
                    af[6] = (short)f2bf(v1.z); af[7] = (short)f2bf(v1.w);
                } else {
                    af = (bf16x8){0, 0, 0, 0, 0, 0, 0, 0};
                }
#pragma unroll
                for (int c = 0; c < NCT; ++c)
                    acc[r][c] = __builtin_amdgcn_mfma_f32_16x16x32_bf16(af, bf[c][t], acc[r][c],
                                                                       0, 0, 0);
            }
        } else {
            const unsigned short* Ar = (const unsigned short*)Av + (size_t)arow * K + quad * 8;
#pragma unroll
            for (int t = 0; t < KST; ++t) {
                bf16x8 af = *(const bf16x8*)(Ar + t * 32);
#pragma unroll
                for (int c = 0; c < NCT; ++c)
                    acc[r][c] = __builtin_amdgcn_mfma_f32_16x16x32_bf16(af, bf[c][t], acc[r][c],
                                                                       0, 0, 0);
            }
        }
    }

    // C/D layout: col = lane&15, row = quad*4 + j
#pragma unroll
    for (int r = 0; r < 4; ++r) {
        int row = n0 + r * 16 + quad * 4;
#pragma unroll
        for (int c = 0; c < NCT; ++c) {
            int col = c0 + c * 16 + lo;
#pragma unroll
            for (int j = 0; j < 4; ++j)
                if (row + j < N) C[(size_t)(row + j) * FOUT + col] = f2bf(acc[r][c][j]);
        }
    }

    // attention-coef partial dots -> LDS -> raw es/ed
    float asv[NCT], adv[NCT];
#pragma unroll
    for (int c = 0; c < NCT; ++c) {
        int col = c0 + c * 16 + lo;
        asv[c] = a_src[col];
        adv[c] = a_dst[col];
    }
#pragma unroll
    for (int r = 0; r < 4; ++r) {
#pragma unroll
        for (int j = 0; j < 4; ++j) {
            float ps = 0.f, pd = 0.f;
#pragma unroll
            for (int c = 0; c < NCT; ++c) { ps += acc[r][c][j] * asv[c]; pd += acc[r][c][j] * adv[c]; }
#pragma unroll
            for (int off = 1; off <= 8; off <<= 1) {
                ps += __shfl_xor(ps, off, 64);
                pd += __shfl_xor(pd, off, 64);
            }
            if (lo == 0) {
                int row_l = r * 16 + quad * 4 + j;
                lds_ps[wave][row_l] = ps;
                lds_pd[wave][row_l] = pd;
            }
        }
    }
    __syncthreads();
    if (tid < 64 * H) {
        int row = tid & 63, h = tid >> 6;
        int n = n0 + row;
        if (n < N) {
            float ps, pd;
            if (H == 2) {
                ps = lds_ps[2 * h][row] + lds_ps[2 * h + 1][row];
                pd = lds_pd[2 * h][row] + lds_pd[2 * h + 1][row];
            } else {
                ps = lds_ps[0][row] + lds_ps[1][row] + lds_ps[2][row] + lds_ps[3][row];
                pd = lds_pd[0][row] + lds_pd[1][row] + lds_pd[2][row] + lds_pd[3][row];
            }
            es[n * H + h] = ps;
            ed[n * H + h] = pd;
        }
    }
}

// ------------------------- GAT aggregation, H=2 (single pass) -------------
// R11-proven form: 4B es gather + in-loop exp, 4-deep explicit unroll.

__global__ void gat_agg_h2(const unsigned short* __restrict__ Hpre,
                           const float* __restrict__ es, const float* __restrict__ ed,
                           const int* __restrict__ rowptr, const int* __restrict__ csr_src,
                           const float* __restrict__ bias, unsigned short* __restrict__ out,
                           int N) {
    int wid = (blockIdx.x * blockDim.x + threadIdx.x) >> 6;
    int lane = threadIdx.x & 63;
    if (wid >= N) return;
    const int rs = rowptr[wid], re = rowptr[wid + 1];
    const int h = lane >> 5;
    const float edn = ed[wid * 2 + h];

    float z = 0.f;
    float4 a0 = {0.f, 0.f, 0.f, 0.f}, a1 = {0.f, 0.f, 0.f, 0.f};
    float4 a2 = {0.f, 0.f, 0.f, 0.f}, a3 = {0.f, 0.f, 0.f, 0.f};
    int i = rs;
    for (; i + 4 <= re; i += 4) {
        int s0 = csr_src[i], s1 = csr_src[i + 1], s2 = csr_src[i + 2], s3 = csr_src[i + 3];
        float e0 = es[s0 * 2 + h] + edn;
        float e1 = es[s1 * 2 + h] + edn;
        float e2 = es[s2 * 2 + h] + edn;
        float e3 = es[s3 * 2 + h] + edn;
        e0 = (e0 > 0.f) ? e0 : 0.2f * e0;
        e1 = (e1 > 0.f) ? e1 : 0.2f * e1;
        e2 = (e2 > 0.f) ? e2 : 0.2f * e2;
        e3 = (e3 > 0.f) ? e3 : 0.2f * e3;
        float w0 = __expf(e0), w1 = __expf(e1), w2 = __expf(e2), w3 = __expf(e3);
        z += (w0 + w1) + (w2 + w3);
        ushort4 u0 = *(const ushort4*)(Hpre + (size_t)s0 * 256 + lane * 4);
        ushort4 u1 = *(const ushort4*)(Hpre + (size_t)s1 * 256 + lane * 4);
        ushort4 u2 = *(const ushort4*)(Hpre + (size_t)s2 * 256 + lane * 4);
        ushort4 u3 = *(const ushort4*)(Hpre + (size_t)s3 * 256 + lane * 4);
        a0.x += w0 * bf2f(u0.x); a0.y += w0 * bf2f(u0.y);
        a0.z += w0 * bf2f(u0.z); a0.w += w0 * bf2f(u0.w);
        a1.x += w1 * bf2f(u1.x); a1.y += w1 * bf2f(u1.y);
        a1.z += w1 * bf2f(u1.z); a1.w += w1 * bf2f(u1.w);
        a2.x += w2 * bf2f(u2.x); a2.y += w2 * bf2f(u2.y);
        a2.z += w2 * bf2f(u2.z); a2.w += w2 * bf2f(u2.w);
        a3.x += w3 * bf2f(u3.x); a3.y += w3 * bf2f(u3.y);
        a3.z += w3 * bf2f(u3.z); a3.w += w3 * bf2f(u3.w);
    }
    for (; i < re; ++i) {
        int s0 = csr_src[i];
        float e0 = es[s0 * 2 + h] + edn;
        e0 = (e0 > 0.f) ? e0 : 0.2f * e0;
        float w0 = __expf(e0);
        z += w0;
        ushort4 u0 = *(const ushort4*)(Hpre + (size_t)s0 * 256 + lane * 4);
        a0.x += w0 * bf2f(u0.x); a0.y += w0 * bf2f(u0.y);
        a0.z += w0 * bf2f(u0.z); a0.w += w0 * bf2f(u0.w);
    }
    const float rz = 1.f / (z + 1e-16f);
    float4 bv = ((const float4*)bias)[lane];
    float ox = (a0.x + a1.x + a2.x + a3.x) * rz + bv.x;
    float oy = (a0.y + a1.y + a2.y + a3.y) * rz + bv.y;
    float oz = (a0.z + a1.z + a2.z + a3.z) * rz + bv.z;
    float ow = (a0.w + a1.w + a2.w + a3.w) * rz + bv.w;
    ox = (ox > 0.f) ? ox : __expf(ox) - 1.f;
    oy = (oy > 0.f) ? oy : __expf(oy) - 1.f;
    oz = (oz > 0.f) ? oz : __expf(oz) - 1.f;
    ow = (ow > 0.f) ? ow : __expf(ow) - 1.f;
    ushort4 o;
    o.x = f2bf(ox); o.y = f2bf(oy); o.z = f2bf(oz); o.w = f2bf(ow);
    *(ushort4*)(out + (size_t)wid * 256 + lane * 4) = o;
}

// ------------------------- GAT aggregation, H=1 (single pass) -------------

__global__ void gat_agg_h1(const unsigned short* __restrict__ Hpre,
                           const float* __restrict__ es, const float* __restrict__ ed,
                           const int* __restrict__ rowptr, const int* __restrict__ csr_src,
                           const float* __restrict__ bias, unsigned short* __restrict__ out,
                           int N) {
    int wid = (blockIdx.x * blockDim.x + threadIdx.x) >> 6;
    int lane = threadIdx.x & 63;
    if (wid >= N) return;
    const int rs = rowptr[wid], re = rowptr[wid + 1];
    const int half = lane >> 5, c = lane & 31;
    const float edn = ed[wid];

    float z = 0.f;
    float4 a0 = {0.f, 0.f, 0.f, 0.f}, a1 = {0.f, 0.f, 0.f, 0.f};
    float4 a2 = {0.f, 0.f, 0.f, 0.f}, a3 = {0.f, 0.f, 0.f, 0.f};
    int i = rs + half;
    for (; i + 6 < re; i += 8) {
        int s0 = csr_src[i], s1 = csr_src[i + 2], s2 = csr_src[i + 4], s3 = csr_src[i + 6];
        float e0 = es[s0] + edn, e1 = es[s1] + edn, e2 = es[s2] + edn, e3 = es[s3] + edn;
        e0 = (e0 > 0.f) ? e0 : 0.2f * e0;
        e1 = (e1 > 0.f) ? e1 : 0.2f * e1;
        e2 = (e2 > 0.f) ? e2 : 0.2f * e2;
        e3 = (e3 > 0.f) ? e3 : 0.2f * e3;
        float w0 = __expf(e0), w1 = __expf(e1), w2 = __expf(e2), w3 = __expf(e3);
        z += (w0 + w1) + (w2 + w3);
        ushort4 u0 = *(const ushort4*)(Hpre + (size_t)s0 * 128 + c * 4);
        ushort4 u1 = *(const ushort4*)(Hpre + (size_t)s1 * 128 + c * 4);
        ushort4 u2 = *(const ushort4*)(Hpre + (size_t)s2 * 128 + c * 4);
        ushort4 u3 = *(const ushort4*)(Hpre + (size_t)s3 * 128 + c * 4);
        a0.x += w0 * bf2f(u0.x); a0.y += w0 * bf2f(u0.y);
        a0.z += w0 * bf2f(u0.z); a0.w += w0 * bf2f(u0.w);
        a1.x += w1 * bf2f(u1.x); a1.y += w1 * bf2f(u1.y);
        a1.z += w1 * bf2f(u1.z); a1.w += w1 * bf2f(u1.w);
        a2.x += w2 * bf2f(u2.x); a2.y += w2 * bf2f(u2.y);
        a2.z += w2 * bf2f(u2.z); a2.w += w2 * bf2f(u2.w);
        a3.x += w3 * bf2f(u3.x); a3.y += w3 * bf2f(u3.y);
        a3.z += w3 * bf2f(u3.z); a3.w += w3 * bf2f(u3.w);
    }
    for (; i < re; i += 2) {
        int s0 = csr_src[i];
        float e0 = es[s0] + edn;
        e0 = (e0 > 0.f) ? e0 : 0.2f * e0;
        float w0 = __expf(e0);
        z += w0;
        ushort4 u0 = *(const ushort4*)(Hpre + (size_t)s0 * 128 + c * 4);
        a0.x += w0 * bf2f(u0.x); a0.y += w0 * bf2f(u0.y);
        a0.z += w0 * bf2f(u0.z); a0.w += w0 * bf2f(u0.w);
    }
    z += __shfl_xor(z, 32, 64);
    const float rz = 1.f / (z + 1e-16f);

    float ox = a0.x + a1.x + a2.x + a3.x;
    float oy = a0.y + a1.y + a2.y + a3.y;
    float oz = a0.z + a1.z + a2.z + a3.z;
    float ow = a0.w + a1.w + a2.w + a3.w;
    ox += __shfl_xor(ox, 32, 64);
    oy += __shfl_xor(oy, 32, 64);
    oz += __shfl_xor(oz, 32, 64);
    ow += __shfl_xor(ow, 32, 64);
    if (lane < 32) {
        float4 bv = ((const float4*)bias)[c];
        ox = ox * rz + bv.x; oy = oy * rz + bv.y; oz = oz * rz + bv.z; ow = ow * rz + bv.w;
        ox = (ox > 0.f) ? ox : __expf(ox) - 1.f;
        oy = (oy > 0.f) ? oy : __expf(oy) - 1.f;
        oz = (oz > 0.f) ? oz : __expf(oz) - 1.f;
        ow = (ow > 0.f) ? ow : __expf(ow) - 1.f;
        ushort4 o;
        o.x = f2bf(ox); o.y = f2bf(oy); o.z = f2bf(oz); o.w = f2bf(ow);
        *(ushort4*)(out + (size_t)wid * 128 + c * 4) = o;
    }
}

// ------------------------- global mean pool (chunk-parallel) --------------

#define PCHUNK 256

__global__ __launch_bounds__(256) void pool_partial(const unsigned short* __restrict__ h2,
                                                    const int* __restrict__ batch,
                                                    float* __restrict__ xsum,
                                                    int* __restrict__ cnt, int N) {
    const int base = blockIdx.x * PCHUNK;
    const int rg = threadIdx.x >> 6;
    const int c2 = threadIdx.x & 63;
    float ax = 0.f, ay = 0.f;
    int gcur = -1, run = 0;
    for (int r = rg; r < PCHUNK; r += 4) {
        int i = base + r;
        if (i >= N) break;
        int g = batch[i];
        if (g != gcur) {
            if (gcur >= 0) {
                atomicAdd(&xsum[gcur * 128 + c2 * 2 + 0], ax);
                atomicAdd(&xsum[gcur * 128 + c2 * 2 + 1], ay);
                if (c2 == 0) atomicAdd(&cnt[gcur], run);
            }
            gcur = g; ax = 0.f; ay = 0.f; run = 0;
        }
        ushort2 u = *(const ushort2*)(h2 + (size_t)i * 128 + c2 * 2);
        ax += bf2f(u.x); ay += bf2f(u.y);
        run += 1;
    }
    if (gcur >= 0) {
        atomicAdd(&xsum[gcur * 128 + c2 * 2 + 0], ax);
        atomicAdd(&xsum[gcur * 128 + c2 * 2 + 1], ay);
        if (c2 == 0) atomicAdd(&cnt[gcur], run);
    }
}

// ------------------------- policy / value heads ---------------------------

__global__ void head_kernel(const float* __restrict__ xsum, const int* __restrict__ cnt,
                            const float* __restrict__ Wp, const float* __restrict__ bp,
                            const float* __restrict__ Wv, const float* __restrict__ bv,
                            float* __restrict__ out) {
    int g = blockIdx.x, t = threadIdx.x;  // 64 threads
    __shared__ float p[128];
    float inv = 1.f / fmaxf((float)cnt[g], 1.f);
    p[t] = xsum[g * 128 + t] * inv;
    p[t + 64] = xsum[g * 128 + t + 64] * inv;
    __syncthreads();
    if (t < 32) {
        float acc = bp[t];
        for (int k = 0; k < 128; ++k) acc += p[k] * Wp[k * 32 + t];
        out[g * 32 + t] = acc;
    } else if (t == 32) {
        float acc = bv[0];
        for (int k = 0; k < 128; ++k) acc += p[k] * Wv[k];
        out[64 * 32 + g] = acc;
    }
}

// ---------------------------------------------------------------------------

extern "C" void kernel_launch(void* const* d_in, const int* in_sizes, int n_in,
                              void* d_out, int out_size, void* d_ws, size_t ws_size,
                              hipStream_t stream) {
    const float* x      = (const float*)d_in[0];
    const int*   ei     = (const int*)d_in[1];
    const int*   batch  = (const int*)d_in[2];
    const float* W1     = (const float*)d_in[3];
    const float* a_src1 = (const float*)d_in[4];
    const float* a_dst1 = (const float*)d_in[5];
    const float* b1     = (const float*)d_in[6];
    const float* W2     = (const float*)d_in[7];
    const float* a_src2 = (const float*)d_in[8];
    const float* a_dst2 = (const float*)d_in[9];
    const float* b2     = (const float*)d_in[10];
    const float* Wp     = (const float*)d_in[11];
    const float* bp     = (const float*)d_in[12];
    const float* Wv     = (const float*)d_in[13];
    const float* bv     = (const float*)d_in[14];

    const int N  = in_sizes[0] / 128;
    const int E  = in_sizes[1] / 2;
    const int ET = E + N;
    const int TILES = (N + 1023) / 1024;
    const int NPAD = ((N + 63) / 64) * 64;
    const int NBLK = NPAD / 64;
    const int SBLK = (ET + 255) / 256;
    const int RSIZE = (N + RANGES - 1) / RANGES;
    const int PBLK = (N + PCHUNK - 1) / PCHUNK;

    char* ws = (char*)d_ws;
    size_t off = 0;
    auto alloc = [&](size_t bytes) -> void* {
        void* p = ws + off;
        off = (off + bytes + 255) & ~(size_t)255;
        return p;
    };
    unsigned short* h1pre = (unsigned short*)alloc((size_t)NPAD * 256 * 2);  // reused as h2pre
    unsigned short* h1bf  = (unsigned short*)alloc((size_t)NPAD * 256 * 2);
    unsigned short* h2bf  = (unsigned short*)alloc((size_t)N * 128 * 2);
    unsigned short* w1sw  = (unsigned short*)alloc((size_t)128 * 256 * 2);
    unsigned short* w2sw  = (unsigned short*)alloc((size_t)256 * 128 * 2);
    float* es1 = (float*)alloc((size_t)N * 2 * 4);
    float* ed1 = (float*)alloc((size_t)N * 2 * 4);
    float* es2 = (float*)alloc((size_t)N * 4);
    float* ed2 = (float*)alloc((size_t)N * 4);
    // contiguous zero region: deg | xsum | cnt
    const int ZINTS = N + 64 * 128 + 64;
    int*   zbase  = (int*)alloc(((size_t)ZINTS + 8) * 4);
    int*   deg    = zbase;
    float* xsum   = (float*)(zbase + N);
    int*   cnt    = (int*)(xsum + 64 * 128);
    int*   rowptr = (int*)alloc((size_t)(N + 1) * 4);
    int*   cursor = (int*)alloc((size_t)N * 4);
    int*   csrsrc = (int*)alloc((size_t)ET * 4);
    int*   tsum   = (int*)alloc(64 * 4);
    unsigned short* h2pre = h1pre;  // h1pre dead after layer-1 agg
    const int zn4 = (ZINTS + 3) / 4;

    // --- init: zero (deg/xsum/cnt) + both weight swizzles, one launch ---
    init_kernel<<<32 + (zn4 + 255) / 256, 256, 0, stream>>>(W1, W2, w1sw, w2sw, zbase, zn4);

    // --- CSR build ---
    degree_kernel<<<(ET + 255) / 256, 256, 0, stream>>>(ei, deg, E, N);
    scan_tiles<<<TILES, 256, 0, stream>>>(deg, tsum, N);
    scan_add<<<TILES, 256, 0, stream>>>(deg, tsum, rowptr, cursor, N, TILES);
    scatter_kernel<<<RANGES * SBLK, 256, 0, stream>>>(ei, cursor, csrsrc, E, N, SBLK, RSIZE);

    // --- layer 1: heads=2 (A = fp32 x, cast in-reg; es1/ed1 from epilogue) ---
    gemm_mfma<128, 256, 2, true><<<NBLK, 256, 0, stream>>>(x, w1sw, a_src1, a_dst1,
                                                           es1, ed1, h1pre, N);
    gat_agg_h2<<<(N + 3) / 4, 256, 0, stream>>>(h1pre, es1, ed1, rowptr, csrsrc, b1,
                                                h1bf, N);

    // --- layer 2: heads=1 ---
    gemm_mfma<256, 128, 1, false><<<NBLK, 256, 0, stream>>>(h1bf, w2sw, a_src2, a_dst2,
                                                            es2, ed2, h2pre, N);
    gat_agg_h1<<<(N + 3) / 4, 256, 0, stream>>>(h2pre, es2, ed2, rowptr, csrsrc, b2,
                                                h2bf, N);

    // --- pool + heads ---
    pool_partial<<<PBLK, 256, 0, stream>>>(h2bf, batch, xsum, cnt, N);
    head_kernel<<<64, 64, 0, stream>>>(xsum, cnt, Wp, bp, Wv, bv, (float*)d_out);
}